// Round 1
// baseline (1531.765 us; speedup 1.0000x reference)
//
#include <hip/hip_runtime.h>
#include <hip/hip_bf16.h>

// NodeGCN: 3x GCNConv(H=20) + BN/ReLU + final linear, N=100K nodes, E=3.2M edges.
// Strategy: build CSR (edges sorted by dst) once per call, then gather-based
// aggregation (no feature atomics). coef factored: out[i] = dinv[i]*(sum_j h[s_j]*w_j
// + h[i]*dinv[i]) + b, with w_j = ew_j*dinv[src_j].

#define HD 20          // hidden dim (hard-coded in reference)
#define EPS 1e-5f

__global__ __launch_bounds__(256)
void init_kernel(float* deg, int* cnt, float* stats, int n) {
    int t = blockIdx.x * blockDim.x + threadIdx.x;
    if (t < n) { deg[t] = 1.0f; cnt[t] = 0; }   // 1.0 = self-loop weight
    if (t < 80) stats[t] = 0.0f;                // sum1,sq1,sum2,sq2
}

__global__ __launch_bounds__(256)
void deg_count_kernel(const int* __restrict__ dst, const float* __restrict__ ew,
                      float* deg, int* cnt, int E) {
    int e = blockIdx.x * blockDim.x + threadIdx.x;
    if (e >= E) return;
    int d = dst[e];
    atomicAdd(&deg[d], ew[e]);
    atomicAdd(&cnt[d], 1);
}

__global__ __launch_bounds__(256)
void dinv_kernel(float* deg, int n) {
    int t = blockIdx.x * blockDim.x + threadIdx.x;
    if (t < n) { float d = deg[t]; deg[t] = (d > 0.0f) ? rsqrtf(d) : 0.0f; }
}

// Single-block exclusive scan of cnt[0..n) -> row_start[0..n]; zeroes cnt (reused as cursor).
__global__ __launch_bounds__(256)
void scan_kernel(int* __restrict__ cnt, int* __restrict__ row_start, int n) {
    const int T = 256;
    int t = threadIdx.x;
    int chunk = (n + T - 1) / T;
    int begin = t * chunk;
    int end = begin + chunk; if (end > n) end = n;
    int s = 0;
    for (int i = begin; i < end; ++i) s += cnt[i];
    __shared__ int partial[T];
    partial[t] = s;
    __syncthreads();
    for (int off = 1; off < T; off <<= 1) {
        int v = (t >= off) ? partial[t - off] : 0;
        __syncthreads();
        partial[t] += v;
        __syncthreads();
    }
    int run = partial[t] - s;   // exclusive prefix for this thread's chunk
    for (int i = begin; i < end; ++i) {
        int c = cnt[i];
        row_start[i] = run;
        run += c;
        cnt[i] = 0;             // becomes the fill cursor
    }
    if (t == 0) row_start[n] = partial[T - 1];
}

__global__ __launch_bounds__(256)
void fill_kernel(const int* __restrict__ src, const int* __restrict__ dst,
                 const float* __restrict__ ew, const float* __restrict__ dinv,
                 const int* __restrict__ row_start, int* cursor,
                 int* __restrict__ ssrc, float* __restrict__ sw, int E) {
    int e = blockIdx.x * blockDim.x + threadIdx.x;
    if (e >= E) return;
    int d = dst[e];
    int s = src[e];
    int pos = atomicAdd(&cursor[d], 1);
    int idx = row_start[d] + pos;
    ssrc[idx] = s;
    sw[idx] = ew[e] * dinv[s];
}

// h[n,20] = in[n,FIN] @ W[FIN,20]
template<int FIN, int NPB>
__global__ __launch_bounds__(256)
void gemm_kernel(const float* __restrict__ in, const float* __restrict__ W,
                 float* __restrict__ h, int n) {
    __shared__ float sW[FIN * HD];
    __shared__ float sIn[NPB * FIN];
    for (int i = threadIdx.x; i < FIN * HD; i += blockDim.x) sW[i] = W[i];
    int base = blockIdx.x * NPB;
    int nb = n - base; if (nb > NPB) nb = NPB;
    int lim = n * FIN;
    int gbase = base * FIN;
    for (int i = threadIdx.x; i < NPB * FIN; i += blockDim.x) {
        int g = gbase + i;
        sIn[i] = (g < lim) ? in[g] : 0.0f;
    }
    __syncthreads();
    for (int idx = threadIdx.x; idx < NPB * HD; idx += blockDim.x) {
        int nl = idx / HD, f = idx % HD;
        if (nl < nb) {
            float acc = 0.0f;
            const float* row = &sIn[nl * FIN];
            #pragma unroll 4
            for (int k = 0; k < FIN; ++k) acc = fmaf(row[k], sW[k * HD + f], acc);
            h[(base + nl) * HD + f] = acc;
        }
    }
}

// out[i,f] = relu(dinv[i]*(h[i,f]*dinv[i] + sum_j h[s_j,f]*w_j) + b[f]); optional BN stats.
template<bool DO_STATS>
__global__ __launch_bounds__(256)
void agg_kernel(const float* __restrict__ h, const float* __restrict__ dinv,
                const int* __restrict__ row_start, const int* __restrict__ ssrc,
                const float* __restrict__ sw, const float* __restrict__ bias,
                float* __restrict__ out, float* __restrict__ stat_sum,
                float* __restrict__ stat_sq, int n) {
    __shared__ float ls[HD], lq[HD];
    if (DO_STATS) {
        if (threadIdx.x < HD) { ls[threadIdx.x] = 0.0f; lq[threadIdx.x] = 0.0f; }
        __syncthreads();
    }
    int t = blockIdx.x * blockDim.x + threadIdx.x;
    bool valid = (t < n * HD);
    float v = 0.0f;
    int f = 0;
    if (valid) {
        int i = t / HD; f = t % HD;
        float di = dinv[i];
        int s0 = row_start[i], s1 = row_start[i + 1];
        float acc = h[t] * di;                 // self-loop: h[i,f]*dinv[i]
        for (int j = s0; j < s1; ++j) {
            acc = fmaf(h[ssrc[j] * HD + f], sw[j], acc);
        }
        v = fmaf(acc, di, bias[f]);
        v = (v > 0.0f) ? v : 0.0f;             // relu
        out[t] = v;
    }
    if (DO_STATS) {
        if (valid) { atomicAdd(&ls[f], v); atomicAdd(&lq[f], v * v); }
        __syncthreads();
        if (threadIdx.x < HD) {
            atomicAdd(&stat_sum[threadIdx.x], ls[threadIdx.x]);
            atomicAdd(&stat_sq[threadIdx.x], lq[threadIdx.x]);
        }
    }
}

__global__ __launch_bounds__(64)
void bn_finalize_kernel(const float* __restrict__ sum, const float* __restrict__ sq,
                        const float* __restrict__ g, const float* __restrict__ be,
                        float* __restrict__ scale, float* __restrict__ shift, int n) {
    int t = threadIdx.x;
    if (t < HD) {
        float inv_n = 1.0f / (float)n;
        float m = sum[t] * inv_n;
        float var = sq[t] * inv_n - m * m;
        float sc = g[t] * rsqrtf(var + EPS);
        scale[t] = sc;
        shift[t] = be[t] - m * sc;
    }
}

__global__ __launch_bounds__(256)
void bn_apply_kernel(const float* __restrict__ in, const float* __restrict__ scale,
                     const float* __restrict__ shift, float* __restrict__ out, int total) {
    int t = blockIdx.x * blockDim.x + threadIdx.x;
    if (t >= total) return;
    int f = t % HD;
    out[t] = fmaf(in[t], scale[f], shift[f]);
}

// out[i,c] = concat(o1,o2,o3)[i,:] @ Wl[60,10] + bl
__global__ __launch_bounds__(256)
void final_kernel(const float* __restrict__ o1, const float* __restrict__ o2,
                  const float* __restrict__ o3, const float* __restrict__ Wl,
                  const float* __restrict__ bl, float* __restrict__ out, int n) {
    __shared__ float sW[60 * 10];
    __shared__ float sb[10];
    for (int i = threadIdx.x; i < 600; i += blockDim.x) sW[i] = Wl[i];
    if (threadIdx.x < 10) sb[threadIdx.x] = bl[threadIdx.x];
    __syncthreads();
    int t = blockIdx.x * blockDim.x + threadIdx.x;
    if (t >= n * 10) return;
    int i = t / 10, c = t % 10;
    float acc = sb[c];
    const float* r1 = o1 + i * HD;
    const float* r2 = o2 + i * HD;
    const float* r3 = o3 + i * HD;
    #pragma unroll
    for (int k = 0; k < HD; ++k) acc = fmaf(r1[k], sW[k * 10 + c], acc);
    #pragma unroll
    for (int k = 0; k < HD; ++k) acc = fmaf(r2[k], sW[(HD + k) * 10 + c], acc);
    #pragma unroll
    for (int k = 0; k < HD; ++k) acc = fmaf(r3[k], sW[(2 * HD + k) * 10 + c], acc);
    out[t] = acc;
}

extern "C" void kernel_launch(void* const* d_in, const int* in_sizes, int n_in,
                              void* d_out, int out_size, void* d_ws, size_t ws_size,
                              hipStream_t stream) {
    const float* x   = (const float*)d_in[0];
    const int*   ei  = (const int*)d_in[1];
    const float* ew  = (const float*)d_in[2];
    const float* W1  = (const float*)d_in[3];
    const float* b1  = (const float*)d_in[4];
    const float* g1  = (const float*)d_in[5];
    const float* be1 = (const float*)d_in[6];
    const float* W2  = (const float*)d_in[7];
    const float* b2  = (const float*)d_in[8];
    const float* g2  = (const float*)d_in[9];
    const float* be2 = (const float*)d_in[10];
    const float* W3  = (const float*)d_in[11];
    const float* b3  = (const float*)d_in[12];
    const float* Wl  = (const float*)d_in[13];
    const float* bl  = (const float*)d_in[14];
    float* out = (float*)d_out;

    const int F = in_sizes[3] / HD;       // 128
    const int N = in_sizes[0] / F;        // 100000
    const int E = in_sizes[2];            // 3200000
    const int* src = ei;
    const int* dst = ei + E;

    // workspace bump allocator
    char* p = (char*)d_ws;
    auto alloc = [&](size_t bytes) -> void* {
        void* r = (void*)p;
        p += (bytes + 255) & ~(size_t)255;
        return r;
    };
    float* deg       = (float*)alloc((size_t)N * 4);          // becomes dinv
    int*   cnt       = (int*)  alloc((size_t)N * 4);          // counts -> cursor
    int*   row_start = (int*)  alloc((size_t)(N + 1) * 4);
    int*   ssrc      = (int*)  alloc((size_t)E * 4);
    float* sw        = (float*)alloc((size_t)E * 4);
    float* h         = (float*)alloc((size_t)N * HD * 4);
    float* agg       = (float*)alloc((size_t)N * HD * 4);
    float* o1        = (float*)alloc((size_t)N * HD * 4);
    float* o2        = (float*)alloc((size_t)N * HD * 4);
    float* o3        = (float*)alloc((size_t)N * HD * 4);
    float* stats     = (float*)alloc(80 * 4);                 // sum1,sq1,sum2,sq2
    float* scsh      = (float*)alloc(40 * 4);                 // scale, shift

    const int B = 256;
    int gN  = (N + B - 1) / B;
    int gE  = (E + B - 1) / B;
    int gNH = (N * HD + B - 1) / B;
    int gNC = (N * 10 + B - 1) / B;

    // graph preprocessing (shared by all 3 conv layers)
    hipLaunchKernelGGL(init_kernel, dim3(gN), dim3(B), 0, stream, deg, cnt, stats, N);
    hipLaunchKernelGGL(deg_count_kernel, dim3(gE), dim3(B), 0, stream, dst, ew, deg, cnt, E);
    hipLaunchKernelGGL(dinv_kernel, dim3(gN), dim3(B), 0, stream, deg, N);
    hipLaunchKernelGGL(scan_kernel, dim3(1), dim3(B), 0, stream, cnt, row_start, N);
    hipLaunchKernelGGL(fill_kernel, dim3(gE), dim3(B), 0, stream,
                       src, dst, ew, deg, row_start, cnt, ssrc, sw, E);

    // layer 1: x[N,128] @ W1 -> conv -> relu -> BN -> o1
    hipLaunchKernelGGL((gemm_kernel<128, 16>), dim3((N + 15) / 16), dim3(B), 0, stream, x, W1, h, N);
    hipLaunchKernelGGL((agg_kernel<true>), dim3(gNH), dim3(B), 0, stream,
                       h, deg, row_start, ssrc, sw, b1, agg, stats, stats + 20, N);
    hipLaunchKernelGGL(bn_finalize_kernel, dim3(1), dim3(64), 0, stream,
                       stats, stats + 20, g1, be1, scsh, scsh + 20, N);
    hipLaunchKernelGGL(bn_apply_kernel, dim3(gNH), dim3(B), 0, stream, agg, scsh, scsh + 20, o1, N * HD);

    // layer 2: o1 @ W2 -> conv -> relu -> BN -> o2
    hipLaunchKernelGGL((gemm_kernel<HD, 64>), dim3((N + 63) / 64), dim3(B), 0, stream, o1, W2, h, N);
    hipLaunchKernelGGL((agg_kernel<true>), dim3(gNH), dim3(B), 0, stream,
                       h, deg, row_start, ssrc, sw, b2, agg, stats + 40, stats + 60, N);
    hipLaunchKernelGGL(bn_finalize_kernel, dim3(1), dim3(64), 0, stream,
                       stats + 40, stats + 60, g2, be2, scsh, scsh + 20, N);
    hipLaunchKernelGGL(bn_apply_kernel, dim3(gNH), dim3(B), 0, stream, agg, scsh, scsh + 20, o2, N * HD);

    // layer 3: o2 @ W3 -> conv -> relu -> o3 (no BN)
    hipLaunchKernelGGL((gemm_kernel<HD, 64>), dim3((N + 63) / 64), dim3(B), 0, stream, o2, W3, h, N);
    hipLaunchKernelGGL((agg_kernel<false>), dim3(gNH), dim3(B), 0, stream,
                       h, deg, row_start, ssrc, sw, b3, o3, nullptr, nullptr, N);

    // final linear: [o1|o2|o3] @ Wl + bl
    hipLaunchKernelGGL(final_kernel, dim3(gNC), dim3(B), 0, stream, o1, o2, o3, Wl, bl, out, N);
}

// Round 2
// 826.831 us; speedup vs baseline: 1.8526x; 1.8526x over previous
//
#include <hip/hip_runtime.h>
#include <hip/hip_bf16.h>

// NodeGCN: 3x GCNConv(H=20) + BN/ReLU + final linear, N=100K, E=3.2M.
// R1 changes vs R0:
//  - deg_count does 1 atomic/edge (cnt only); deg computed post-sort as a
//    contiguous segment sum (dinv[src] factored out: hs = h*dinv prescale).
//  - parallel 3-kernel scan (was 1 block).
//  - CSR payload packed int2 (src, ew-bits); agg gathers float4 (4 feats/thread).
//  - float4 staging in gemm, float4 bn_apply; dinv prescale fused in gemm epilogue.

#define HD 20
#define EPS 1e-5f

__global__ __launch_bounds__(256)
void init_kernel(int* cnt, float* stats, int n) {
    int t = blockIdx.x * blockDim.x + threadIdx.x;
    if (t < n) cnt[t] = 0;
    if (t < 80) stats[t] = 0.0f;
}

// one atomic per edge (count only), int4-vectorized dst reads
__global__ __launch_bounds__(256)
void deg_count_kernel(const int* __restrict__ dst, int* cnt, int E) {
    int t = blockIdx.x * blockDim.x + threadIdx.x;
    int base = t * 4;
    if (base + 3 < E) {
        int4 d = *(const int4*)(dst + base);
        atomicAdd(&cnt[d.x], 1);
        atomicAdd(&cnt[d.y], 1);
        atomicAdd(&cnt[d.z], 1);
        atomicAdd(&cnt[d.w], 1);
    } else {
        for (int e = base; e < E; ++e) atomicAdd(&cnt[dst[e]], 1);
    }
}

// ---- 3-kernel exclusive scan of cnt -> row_start ----
__global__ __launch_bounds__(256)
void scan1_kernel(const int* __restrict__ cnt, int* __restrict__ bsum, int n) {
    __shared__ int red[256];
    int t = threadIdx.x;
    int g = blockIdx.x * 256 + t;
    red[t] = (g < n) ? cnt[g] : 0;
    __syncthreads();
    for (int off = 128; off > 0; off >>= 1) {
        if (t < off) red[t] += red[t + off];
        __syncthreads();
    }
    if (t == 0) bsum[blockIdx.x] = red[0];
}

__global__ __launch_bounds__(512)
void scan2_kernel(int* bsum, int nb) {
    __shared__ int s[512];
    int t = threadIdx.x;
    int v = (t < nb) ? bsum[t] : 0;
    s[t] = v;
    __syncthreads();
    for (int off = 1; off < 512; off <<= 1) {
        int u = (t >= off) ? s[t - off] : 0;
        __syncthreads();
        s[t] += u;
        __syncthreads();
    }
    if (t < nb) bsum[t] = s[t] - v;   // exclusive
}

__global__ __launch_bounds__(256)
void scan3_kernel(int* __restrict__ cnt, const int* __restrict__ bsum,
                  int* __restrict__ row_start, int n) {
    __shared__ int s[256];
    int t = threadIdx.x;
    int g = blockIdx.x * 256 + t;
    int v = (g < n) ? cnt[g] : 0;
    s[t] = v;
    __syncthreads();
    for (int off = 1; off < 256; off <<= 1) {
        int u = (t >= off) ? s[t - off] : 0;
        __syncthreads();
        s[t] += u;
        __syncthreads();
    }
    int incl = s[t];
    if (g < n) {
        row_start[g] = bsum[blockIdx.x] + incl - v;
        cnt[g] = 0;                 // becomes fill cursor
    }
    if (g == n - 1) row_start[n] = bsum[blockIdx.x] + incl;
}

// scatter edges into dst-sorted CSR; payload (src, ew) packed, no dinv needed
__global__ __launch_bounds__(256)
void fill_kernel(const int* __restrict__ src, const int* __restrict__ dst,
                 const float* __restrict__ ew, const int* __restrict__ row_start,
                 int* cursor, int2* __restrict__ se, int E) {
    int e = blockIdx.x * blockDim.x + threadIdx.x;
    if (e >= E) return;
    int d = dst[e];
    int pos = atomicAdd(&cursor[d], 1);
    se[row_start[d] + pos] = make_int2(src[e], __float_as_int(ew[e]));
}

// deg[i] = 1 + sum of ew over row i (contiguous, no atomics); store dinv
__global__ __launch_bounds__(256)
void degdinv_kernel(const int2* __restrict__ se, const int* __restrict__ row_start,
                    float* __restrict__ dinv, int n) {
    int i = blockIdx.x * blockDim.x + threadIdx.x;
    if (i >= n) return;
    int s0 = row_start[i], s1 = row_start[i + 1];
    float d = 1.0f;
    for (int j = s0; j < s1; ++j) d += __int_as_float(se[j].y);
    dinv[i] = rsqrtf(d);            // d >= 1 always
}

// hs[n,20] = (in[n,FIN] @ W[FIN,20]) * dinv[n]   (prescaled output)
template<int FIN, int NPB>
__global__ __launch_bounds__(256)
void gemm_kernel(const float* __restrict__ in, const float* __restrict__ W,
                 const float* __restrict__ dinv, float* __restrict__ hs, int n) {
    __shared__ float sW[FIN * HD];
    __shared__ float sIn[NPB * FIN];
    for (int i = threadIdx.x; i < (FIN * HD) / 4; i += blockDim.x)
        *(float4*)&sW[i * 4] = *(const float4*)&W[i * 4];
    int base = blockIdx.x * NPB;
    int nb = n - base; if (nb > NPB) nb = NPB;
    int lim = n * FIN;
    int gbase = base * FIN;
    for (int i = threadIdx.x; i < (NPB * FIN) / 4; i += blockDim.x) {
        int g = gbase + i * 4;
        *(float4*)&sIn[i * 4] = (g < lim) ? *(const float4*)&in[g]
                                          : make_float4(0.f, 0.f, 0.f, 0.f);
    }
    __syncthreads();
    for (int idx = threadIdx.x; idx < NPB * HD; idx += blockDim.x) {
        int nl = idx / HD, f = idx % HD;
        if (nl < nb) {
            float acc = 0.0f;
            const float* row = &sIn[nl * FIN];
            #pragma unroll 4
            for (int k = 0; k < FIN; ++k) acc = fmaf(row[k], sW[k * HD + f], acc);
            hs[(base + nl) * HD + f] = acc * dinv[base + nl];
        }
    }
}

// thread = (node i, feature quad q). out[i,4q..4q+3] =
//   relu(dinv[i]*(hs[i] + sum_j hs[src_j]*ew_j) + b); optional BN partial stats.
template<bool DO_STATS>
__global__ __launch_bounds__(256)
void agg_kernel(const float* __restrict__ hs, const float* __restrict__ dinv,
                const int* __restrict__ row_start, const int2* __restrict__ se,
                const float* __restrict__ bias, float* __restrict__ out,
                float* __restrict__ stat_sum, float* __restrict__ stat_sq, int n) {
    __shared__ float ls[HD], lq[HD];
    if (DO_STATS) {
        if (threadIdx.x < HD) { ls[threadIdx.x] = 0.0f; lq[threadIdx.x] = 0.0f; }
        __syncthreads();
    }
    int t = blockIdx.x * blockDim.x + threadIdx.x;
    int i = t / 5, q = t % 5;
    const float4* hs4 = (const float4*)hs;   // hs4[i*5+q] = hs[i*20+4q ..]
    if (i < n) {
        float di = dinv[i];
        int s0 = row_start[i], s1 = row_start[i + 1];
        float4 acc = hs4[i * 5 + q];         // self-loop term hs[i]
        int j = s0;
        for (; j + 1 < s1; j += 2) {
            int2 e0 = se[j], e1 = se[j + 1];
            float4 v0 = hs4[e0.x * 5 + q];
            float4 v1 = hs4[e1.x * 5 + q];
            float w0 = __int_as_float(e0.y), w1 = __int_as_float(e1.y);
            acc.x = fmaf(v0.x, w0, acc.x); acc.y = fmaf(v0.y, w0, acc.y);
            acc.z = fmaf(v0.z, w0, acc.z); acc.w = fmaf(v0.w, w0, acc.w);
            acc.x = fmaf(v1.x, w1, acc.x); acc.y = fmaf(v1.y, w1, acc.y);
            acc.z = fmaf(v1.z, w1, acc.z); acc.w = fmaf(v1.w, w1, acc.w);
        }
        if (j < s1) {
            int2 e0 = se[j];
            float4 v0 = hs4[e0.x * 5 + q];
            float w0 = __int_as_float(e0.y);
            acc.x = fmaf(v0.x, w0, acc.x); acc.y = fmaf(v0.y, w0, acc.y);
            acc.z = fmaf(v0.z, w0, acc.z); acc.w = fmaf(v0.w, w0, acc.w);
        }
        float4 bb = *(const float4*)(bias + 4 * q);
        float4 v;
        v.x = fmaxf(fmaf(acc.x, di, bb.x), 0.0f);
        v.y = fmaxf(fmaf(acc.y, di, bb.y), 0.0f);
        v.z = fmaxf(fmaf(acc.z, di, bb.z), 0.0f);
        v.w = fmaxf(fmaf(acc.w, di, bb.w), 0.0f);
        ((float4*)out)[i * 5 + q] = v;
        if (DO_STATS) {
            int f = 4 * q;
            atomicAdd(&ls[f + 0], v.x); atomicAdd(&lq[f + 0], v.x * v.x);
            atomicAdd(&ls[f + 1], v.y); atomicAdd(&lq[f + 1], v.y * v.y);
            atomicAdd(&ls[f + 2], v.z); atomicAdd(&lq[f + 2], v.z * v.z);
            atomicAdd(&ls[f + 3], v.w); atomicAdd(&lq[f + 3], v.w * v.w);
        }
    }
    if (DO_STATS) {
        __syncthreads();
        if (threadIdx.x < HD) {
            atomicAdd(&stat_sum[threadIdx.x], ls[threadIdx.x]);
            atomicAdd(&stat_sq[threadIdx.x], lq[threadIdx.x]);
        }
    }
}

__global__ __launch_bounds__(64)
void bn_finalize_kernel(const float* __restrict__ sum, const float* __restrict__ sq,
                        const float* __restrict__ g, const float* __restrict__ be,
                        float* __restrict__ scale, float* __restrict__ shift, int n) {
    int t = threadIdx.x;
    if (t < HD) {
        float inv_n = 1.0f / (float)n;
        float m = sum[t] * inv_n;
        float var = sq[t] * inv_n - m * m;
        float sc = g[t] * rsqrtf(var + EPS);
        scale[t] = sc;
        shift[t] = be[t] - m * sc;
    }
}

__global__ __launch_bounds__(256)
void bn_apply_kernel(const float4* __restrict__ in, const float* __restrict__ scale,
                     const float* __restrict__ shift, float4* __restrict__ out, int n5) {
    int t = blockIdx.x * blockDim.x + threadIdx.x;
    if (t >= n5) return;
    int q = t % 5;
    float4 v = in[t];
    float4 sc = *(const float4*)(scale + 4 * q);
    float4 sh = *(const float4*)(shift + 4 * q);
    v.x = fmaf(v.x, sc.x, sh.x);
    v.y = fmaf(v.y, sc.y, sh.y);
    v.z = fmaf(v.z, sc.z, sh.z);
    v.w = fmaf(v.w, sc.w, sh.w);
    out[t] = v;
}

// out[i,c] = concat(o1,o2,o3)[i,:] @ Wl[60,10] + bl
__global__ __launch_bounds__(256)
void final_kernel(const float* __restrict__ o1, const float* __restrict__ o2,
                  const float* __restrict__ o3, const float* __restrict__ Wl,
                  const float* __restrict__ bl, float* __restrict__ out, int n) {
    __shared__ float sW[60 * 10];
    __shared__ float sb[10];
    for (int i = threadIdx.x; i < 600; i += blockDim.x) sW[i] = Wl[i];
    if (threadIdx.x < 10) sb[threadIdx.x] = bl[threadIdx.x];
    __syncthreads();
    int t = blockIdx.x * blockDim.x + threadIdx.x;
    if (t >= n * 10) return;
    int i = t / 10, c = t % 10;
    float acc = sb[c];
    const float* r1 = o1 + i * HD;
    const float* r2 = o2 + i * HD;
    const float* r3 = o3 + i * HD;
    #pragma unroll
    for (int k = 0; k < HD; ++k) acc = fmaf(r1[k], sW[k * 10 + c], acc);
    #pragma unroll
    for (int k = 0; k < HD; ++k) acc = fmaf(r2[k], sW[(HD + k) * 10 + c], acc);
    #pragma unroll
    for (int k = 0; k < HD; ++k) acc = fmaf(r3[k], sW[(2 * HD + k) * 10 + c], acc);
    out[t] = acc;
}

extern "C" void kernel_launch(void* const* d_in, const int* in_sizes, int n_in,
                              void* d_out, int out_size, void* d_ws, size_t ws_size,
                              hipStream_t stream) {
    const float* x   = (const float*)d_in[0];
    const int*   ei  = (const int*)d_in[1];
    const float* ew  = (const float*)d_in[2];
    const float* W1  = (const float*)d_in[3];
    const float* b1  = (const float*)d_in[4];
    const float* g1  = (const float*)d_in[5];
    const float* be1 = (const float*)d_in[6];
    const float* W2  = (const float*)d_in[7];
    const float* b2  = (const float*)d_in[8];
    const float* g2  = (const float*)d_in[9];
    const float* be2 = (const float*)d_in[10];
    const float* W3  = (const float*)d_in[11];
    const float* b3  = (const float*)d_in[12];
    const float* Wl  = (const float*)d_in[13];
    const float* bl  = (const float*)d_in[14];
    float* out = (float*)d_out;

    const int F = in_sizes[3] / HD;       // 128
    const int N = in_sizes[0] / F;        // 100000
    const int E = in_sizes[2];            // 3200000
    const int* src = ei;
    const int* dst = ei + E;

    char* p = (char*)d_ws;
    auto alloc = [&](size_t bytes) -> void* {
        void* r = (void*)p;
        p += (bytes + 255) & ~(size_t)255;
        return r;
    };
    float* dinv      = (float*)alloc((size_t)N * 4);
    int*   cnt       = (int*)  alloc((size_t)N * 4);          // counts -> cursor
    int*   row_start = (int*)  alloc((size_t)(N + 1) * 4);
    int2*  se        = (int2*) alloc((size_t)E * 8);          // (src, ew-bits), dst-sorted
    float* hs        = (float*)alloc((size_t)N * HD * 4);
    float* agg       = (float*)alloc((size_t)N * HD * 4);
    float* o1        = (float*)alloc((size_t)N * HD * 4);
    float* o2        = (float*)alloc((size_t)N * HD * 4);
    float* o3        = (float*)alloc((size_t)N * HD * 4);
    float* stats     = (float*)alloc(80 * 4);
    float* scsh      = (float*)alloc(40 * 4);
    int*   bsum      = (int*)  alloc(1024 * 4);

    const int B = 256;
    int gN   = (N + B - 1) / B;                 // 391
    int gE   = (E + B - 1) / B;
    int gE4  = (E / 4 + B - 1) / B;
    int gN5  = (N * 5 + B - 1) / B;
    int gNC  = (N * 10 + B - 1) / B;

    // graph preprocessing (shared by all 3 conv layers)
    hipLaunchKernelGGL(init_kernel, dim3(gN), dim3(B), 0, stream, cnt, stats, N);
    hipLaunchKernelGGL(deg_count_kernel, dim3(gE4), dim3(B), 0, stream, dst, cnt, E);
    hipLaunchKernelGGL(scan1_kernel, dim3(gN), dim3(B), 0, stream, cnt, bsum, N);
    hipLaunchKernelGGL(scan2_kernel, dim3(1), dim3(512), 0, stream, bsum, gN);
    hipLaunchKernelGGL(scan3_kernel, dim3(gN), dim3(B), 0, stream, cnt, bsum, row_start, N);
    hipLaunchKernelGGL(fill_kernel, dim3(gE), dim3(B), 0, stream,
                       src, dst, ew, row_start, cnt, se, E);
    hipLaunchKernelGGL(degdinv_kernel, dim3(gN), dim3(B), 0, stream, se, row_start, dinv, N);

    // layer 1
    hipLaunchKernelGGL((gemm_kernel<128, 16>), dim3((N + 15) / 16), dim3(B), 0, stream,
                       x, W1, dinv, hs, N);
    hipLaunchKernelGGL((agg_kernel<true>), dim3(gN5), dim3(B), 0, stream,
                       hs, dinv, row_start, se, b1, agg, stats, stats + 20, N);
    hipLaunchKernelGGL(bn_finalize_kernel, dim3(1), dim3(64), 0, stream,
                       stats, stats + 20, g1, be1, scsh, scsh + 20, N);
    hipLaunchKernelGGL(bn_apply_kernel, dim3(gN5), dim3(B), 0, stream,
                       (const float4*)agg, scsh, scsh + 20, (float4*)o1, N * 5);

    // layer 2
    hipLaunchKernelGGL((gemm_kernel<HD, 64>), dim3((N + 63) / 64), dim3(B), 0, stream,
                       o1, W2, dinv, hs, N);
    hipLaunchKernelGGL((agg_kernel<true>), dim3(gN5), dim3(B), 0, stream,
                       hs, dinv, row_start, se, b2, agg, stats + 40, stats + 60, N);
    hipLaunchKernelGGL(bn_finalize_kernel, dim3(1), dim3(64), 0, stream,
                       stats + 40, stats + 60, g2, be2, scsh, scsh + 20, N);
    hipLaunchKernelGGL(bn_apply_kernel, dim3(gN5), dim3(B), 0, stream,
                       (const float4*)agg, scsh, scsh + 20, (float4*)o2, N * 5);

    // layer 3 (no BN)
    hipLaunchKernelGGL((gemm_kernel<HD, 64>), dim3((N + 63) / 64), dim3(B), 0, stream,
                       o2, W3, dinv, hs, N);
    hipLaunchKernelGGL((agg_kernel<false>), dim3(gN5), dim3(B), 0, stream,
                       hs, dinv, row_start, se, b3, o3, nullptr, nullptr, N);

    // final linear
    hipLaunchKernelGGL(final_kernel, dim3(gNC), dim3(B), 0, stream, o1, o2, o3, Wl, bl, out, N);
}

// Round 4
// 691.236 us; speedup vs baseline: 2.2160x; 1.1962x over previous
//
#include <hip/hip_runtime.h>
#include <hip/hip_bf16.h>

// NodeGCN: 3x GCNConv(H=20) + BN/ReLU + final linear, N=100K, E=3.2M.
// R3 = R2 with the BN-folding bug fixed:
//  - BN scale folds into next W (exact). BN *shift* becomes cvec[f] = sh@W,
//    added to h BEFORE the dinv prescale/aggregation (it must flow through the
//    graph coefficients; post-agg bias folding was wrong since row sums != 1).
//  - Post-agg bias is the raw layer bias again.
// R2 structure retained: bucketed counting sort CSR build, thread-pair agg,
// LDS-transposed gemm, BN folded into final linear (that fold IS exact).

#define HD 20
#define EPS 1e-5f
#define BSH 7            // 128 nodes per bucket
#define NBMAX 1024
#define CAP 8192         // max edges per bucket held in LDS (mean ~4092)

__global__ __launch_bounds__(1024)
void init_kernel(int* bcnt, float* stats, float* zero20, int nbv) {
    int t = threadIdx.x;
    if (t < nbv) bcnt[t] = 0;
    if (t < 80) stats[t] = 0.0f;
    if (t < HD) zero20[t] = 0.0f;
}

__global__ __launch_bounds__(256)
void bucket_hist_kernel(const int* __restrict__ dst, int* __restrict__ bcnt,
                        int E, int chunk, int nbv) {
    __shared__ int lh[NBMAX];
    for (int i = threadIdx.x; i < nbv; i += 256) lh[i] = 0;
    __syncthreads();
    int s = blockIdx.x * chunk;
    int e = s + chunk; if (e > E) e = E;
    for (int j = s + threadIdx.x; j < e; j += 256)
        atomicAdd(&lh[dst[j] >> BSH], 1);
    __syncthreads();
    for (int i = threadIdx.x; i < nbv; i += 256)
        if (lh[i]) atomicAdd(&bcnt[i], lh[i]);
}

// single block: exclusive scan bcnt[0..nbv) -> bstart, init bcur, row_start[N]=E
__global__ __launch_bounds__(1024)
void bucket_scan_kernel(const int* __restrict__ bcnt, int* __restrict__ bstart,
                        int* __restrict__ bcur, int* __restrict__ row_start,
                        int n, int E, int nbv) {
    __shared__ int s[1024];
    int t = threadIdx.x;
    int v = (t < nbv) ? bcnt[t] : 0;
    s[t] = v;
    __syncthreads();
    for (int off = 1; off < 1024; off <<= 1) {
        int u = (t >= off) ? s[t - off] : 0;
        __syncthreads();
        s[t] += u;
        __syncthreads();
    }
    if (t < nbv) { int st = s[t] - v; bstart[t] = st; bcur[t] = st; }
    if (t == 0) { bstart[nbv] = E; row_start[n] = E; }
}

// scatter edges into bucket-grouped tmp; payload packed (src | local<<20, ew)
__global__ __launch_bounds__(256)
void scatter_kernel(const int* __restrict__ src, const int* __restrict__ dst,
                    const float* __restrict__ ew, int* __restrict__ bcur,
                    int2* __restrict__ tmp, int E, int chunk, int nbv) {
    __shared__ int lh[NBMAX];
    __shared__ int lbase[NBMAX];
    for (int i = threadIdx.x; i < nbv; i += 256) lh[i] = 0;
    __syncthreads();
    int s = blockIdx.x * chunk;
    int e = s + chunk; if (e > E) e = E;
    for (int j = s + threadIdx.x; j < e; j += 256)
        atomicAdd(&lh[dst[j] >> BSH], 1);
    __syncthreads();
    for (int i = threadIdx.x; i < nbv; i += 256) {
        int c = lh[i];
        lbase[i] = c ? atomicAdd(&bcur[i], c) : 0;
        lh[i] = 0;                         // reuse as local cursor
    }
    __syncthreads();
    for (int j = s + threadIdx.x; j < e; j += 256) {
        int d = dst[j];
        int b = d >> BSH;
        int pos = atomicAdd(&lh[b], 1);
        tmp[lbase[b] + pos] = make_int2(src[j] | ((d & ((1 << BSH) - 1)) << 20),
                                        __float_as_int(ew[j]));
    }
}

// one block per bucket: in-LDS counting sort by local dst; emit CSR + row_start + dinv
__global__ __launch_bounds__(256)
void finalize_kernel(const int2* __restrict__ tmp, const int* __restrict__ bstart,
                     int2* __restrict__ se, int* __restrict__ row_start,
                     float* __restrict__ dinv, int n) {
    __shared__ int hist[128];
    __shared__ float degs[128];
    __shared__ int off[128];
    __shared__ int cur[128];
    __shared__ int2 stage[CAP];
    int b = blockIdx.x;
    int s0 = bstart[b], s1 = bstart[b + 1];
    int cnt = s1 - s0;
    int t = threadIdx.x;
    if (t < 128) { hist[t] = 0; degs[t] = 0.0f; cur[t] = 0; }
    __syncthreads();
    for (int j = s0 + t; j < s1; j += 256) {
        int2 r = tmp[j];
        int l = r.x >> 20;
        atomicAdd(&hist[l], 1);
        atomicAdd(&degs[l], __int_as_float(r.y));
    }
    __syncthreads();
    if (t < 128) off[t] = hist[t];
    __syncthreads();
    for (int o = 1; o < 128; o <<= 1) {           // inclusive scan
        int u = (t < 128 && t >= o) ? off[t - o] : 0;
        __syncthreads();
        if (t < 128) off[t] += u;
        __syncthreads();
    }
    if (t < 128) {
        int node = (b << BSH) + t;
        if (node < n) {
            row_start[node] = s0 + off[t] - hist[t];   // exclusive
            dinv[node] = rsqrtf(1.0f + degs[t]);
        }
    }
    __syncthreads();
    if (cnt <= CAP) {
        for (int j = s0 + t; j < s1; j += 256) {
            int2 r = tmp[j];
            int l = r.x >> 20;
            int p = (off[l] - hist[l]) + atomicAdd(&cur[l], 1);
            stage[p] = make_int2(r.x & 0xFFFFF, r.y);
        }
        __syncthreads();
        for (int k = t; k < cnt; k += 256) se[s0 + k] = stage[k];
    } else {   // overflow fallback (correctness net; not taken for this input)
        for (int j = s0 + t; j < s1; j += 256) {
            int2 r = tmp[j];
            int l = r.x >> 20;
            int p = (off[l] - hist[l]) + atomicAdd(&cur[l], 1);
            se[s0 + p] = make_int2(r.x & 0xFFFFF, r.y);
        }
    }
}

// hs[n,20] = ((in[n,FIN] @ W[FIN,20]) + cvec) * dinv[n]
// cvec carries the folded upstream-BN shift (sh @ W); zero for layer 1.
template<int FIN, int NPB>
__global__ __launch_bounds__(256)
void gemm_kernel(const float* __restrict__ in, const float* __restrict__ W,
                 const float* __restrict__ cvec, const float* __restrict__ dinv,
                 float* __restrict__ hs, int n) {
    __shared__ float sWt[HD][FIN + 4];
    __shared__ float sIn[NPB][FIN + 4];
    __shared__ float sC[HD];
    for (int i = threadIdx.x; i < FIN * HD; i += 256) {
        int k = i / HD, f = i % HD;           // W row-major [k][f]
        sWt[f][k] = W[i];
    }
    if (threadIdx.x < HD) sC[threadIdx.x] = cvec[threadIdx.x];
    int base = blockIdx.x * NPB;
    int nb = n - base; if (nb > NPB) nb = NPB;
    int lim = n * FIN;
    const int Q = FIN / 4;
    for (int i = threadIdx.x; i < NPB * Q; i += 256) {
        int row = i / Q, c = (i % Q) * 4;
        int g = (base + row) * FIN + c;
        *(float4*)&sIn[row][c] = (g < lim) ? *(const float4*)&in[g]
                                           : make_float4(0.f, 0.f, 0.f, 0.f);
    }
    __syncthreads();
    for (int idx = threadIdx.x; idx < NPB * HD; idx += 256) {
        int nl = idx / HD, f = idx % HD;
        float4 a = make_float4(0.f, 0.f, 0.f, 0.f);
        #pragma unroll 4
        for (int k = 0; k < FIN; k += 4) {
            float4 x4 = *(const float4*)&sIn[nl][k];
            float4 w4 = *(const float4*)&sWt[f][k];
            a.x = fmaf(x4.x, w4.x, a.x);
            a.y = fmaf(x4.y, w4.y, a.y);
            a.z = fmaf(x4.z, w4.z, a.z);
            a.w = fmaf(x4.w, w4.w, a.w);
        }
        if (nl < nb)
            hs[(base + nl) * HD + f] =
                (((a.x + a.y) + (a.z + a.w)) + sC[f]) * dinv[base + nl];
    }
}

#define FMA4(A, V, W) \
    A.x = fmaf(V.x, W, A.x); A.y = fmaf(V.y, W, A.y); \
    A.z = fmaf(V.z, W, A.z); A.w = fmaf(V.w, W, A.w);

// one node per thread-pair; halves take alternate edges; shfl_xor combine.
template<bool DO_STATS>
__global__ __launch_bounds__(256)
void agg_kernel(const float4* __restrict__ hs4, const float* __restrict__ dinv,
                const int* __restrict__ row_start, const int2* __restrict__ se,
                const float* __restrict__ bias, float4* __restrict__ out,
                float* __restrict__ stat_sum, float* __restrict__ stat_sq, int n) {
    __shared__ float ls[HD], lq[HD];
    if (DO_STATS) {
        if (threadIdx.x < HD) { ls[threadIdx.x] = 0.0f; lq[threadIdx.x] = 0.0f; }
        __syncthreads();
    }
    int t = blockIdx.x * blockDim.x + threadIdx.x;
    int i = t >> 1, half = t & 1;
    if (i < n) {
        float di = dinv[i];
        int s0 = row_start[i], s1 = row_start[i + 1];
        float4 a0, a1, a2, a3, a4;
        if (half == 0) {
            const float4* s = hs4 + i * 5;
            a0 = s[0]; a1 = s[1]; a2 = s[2]; a3 = s[3]; a4 = s[4];
        } else {
            a0 = a1 = a2 = a3 = a4 = make_float4(0.f, 0.f, 0.f, 0.f);
        }
        for (int j = s0 + half; j < s1; j += 2) {
            int2 e = se[j];
            float w = __int_as_float(e.y);
            const float4* r = hs4 + e.x * 5;
            float4 v0 = r[0], v1 = r[1], v2 = r[2], v3 = r[3], v4 = r[4];
            FMA4(a0, v0, w) FMA4(a1, v1, w) FMA4(a2, v2, w)
            FMA4(a3, v3, w) FMA4(a4, v4, w)
        }
        a0.x += __shfl_xor(a0.x, 1); a0.y += __shfl_xor(a0.y, 1);
        a0.z += __shfl_xor(a0.z, 1); a0.w += __shfl_xor(a0.w, 1);
        a1.x += __shfl_xor(a1.x, 1); a1.y += __shfl_xor(a1.y, 1);
        a1.z += __shfl_xor(a1.z, 1); a1.w += __shfl_xor(a1.w, 1);
        a2.x += __shfl_xor(a2.x, 1); a2.y += __shfl_xor(a2.y, 1);
        a2.z += __shfl_xor(a2.z, 1); a2.w += __shfl_xor(a2.w, 1);
        a3.x += __shfl_xor(a3.x, 1); a3.y += __shfl_xor(a3.y, 1);
        a3.z += __shfl_xor(a3.z, 1); a3.w += __shfl_xor(a3.w, 1);
        a4.x += __shfl_xor(a4.x, 1); a4.y += __shfl_xor(a4.y, 1);
        a4.z += __shfl_xor(a4.z, 1); a4.w += __shfl_xor(a4.w, 1);
        if (half == 0) {
            float4 acc[5] = {a0, a1, a2, a3, a4};
            #pragma unroll
            for (int q = 0; q < 5; ++q) {
                float4 bb = *(const float4*)(bias + 4 * q);
                float4 v;
                v.x = fmaxf(fmaf(acc[q].x, di, bb.x), 0.0f);
                v.y = fmaxf(fmaf(acc[q].y, di, bb.y), 0.0f);
                v.z = fmaxf(fmaf(acc[q].z, di, bb.z), 0.0f);
                v.w = fmaxf(fmaf(acc[q].w, di, bb.w), 0.0f);
                out[i * 5 + q] = v;
                if (DO_STATS) {
                    int f = 4 * q;
                    atomicAdd(&ls[f + 0], v.x); atomicAdd(&lq[f + 0], v.x * v.x);
                    atomicAdd(&ls[f + 1], v.y); atomicAdd(&lq[f + 1], v.y * v.y);
                    atomicAdd(&ls[f + 2], v.z); atomicAdd(&lq[f + 2], v.z * v.z);
                    atomicAdd(&ls[f + 3], v.w); atomicAdd(&lq[f + 3], v.w * v.w);
                }
            }
        }
    }
    if (DO_STATS) {
        __syncthreads();
        if (threadIdx.x < HD) {
            atomicAdd(&stat_sum[threadIdx.x], ls[threadIdx.x]);
            atomicAdd(&stat_sq[threadIdx.x], lq[threadIdx.x]);
        }
    }
}

__global__ __launch_bounds__(64)
void bn_finalize_kernel(const float* __restrict__ sum, const float* __restrict__ sq,
                        const float* __restrict__ g, const float* __restrict__ be,
                        float* __restrict__ scale, float* __restrict__ shift, int n) {
    int t = threadIdx.x;
    if (t < HD) {
        float inv_n = 1.0f / (float)n;
        float m = sum[t] * inv_n;
        float var = sq[t] * inv_n - m * m;
        float sc = g[t] * rsqrtf(var + EPS);
        scale[t] = sc;
        shift[t] = be[t] - m * sc;
    }
}

// Wp[k][f] = sc[k]*W[k][f];  cvec[f] = sum_k sh[k]*W[k][f]   (20x20)
// cvec is applied pre-aggregation in the next gemm (NOT folded into post-agg bias).
__global__ __launch_bounds__(512)
void adjust_w_kernel(const float* __restrict__ W, const float* __restrict__ sc,
                     const float* __restrict__ sh, float* __restrict__ Wp,
                     float* __restrict__ cvec) {
    int t = threadIdx.x;
    if (t < HD * HD) Wp[t] = sc[t / HD] * W[t];
    if (t < HD) {
        float acc = 0.0f;
        #pragma unroll
        for (int k = 0; k < HD; ++k) acc = fmaf(sh[k], W[k * HD + t], acc);
        cvec[t] = acc;
    }
}

// Wlp rows 0..19 *= sc1, 20..39 *= sc2; blp = bl + sh1@Wl[0:20] + sh2@Wl[20:40]
// (no aggregation after the final linear, so this constant fold IS exact)
__global__ __launch_bounds__(640)
void adjust_final_kernel(const float* __restrict__ Wl, const float* __restrict__ bl,
                         const float* __restrict__ scsh,
                         float* __restrict__ Wlp, float* __restrict__ blp) {
    int t = threadIdx.x;
    if (t < 600) {
        int k = t / 10;
        float s = (k < 20) ? scsh[k] : (k < 40) ? scsh[40 + (k - 20)] : 1.0f;
        Wlp[t] = s * Wl[t];
    }
    if (t < 10) {
        float acc = bl[t];
        #pragma unroll
        for (int k = 0; k < HD; ++k) acc = fmaf(scsh[20 + k], Wl[k * 10 + t], acc);
        #pragma unroll
        for (int k = 0; k < HD; ++k) acc = fmaf(scsh[60 + k], Wl[(HD + k) * 10 + t], acc);
        blp[t] = acc;
    }
}

__global__ __launch_bounds__(256)
void final_kernel(const float* __restrict__ o1, const float* __restrict__ o2,
                  const float* __restrict__ o3, const float* __restrict__ Wl,
                  const float* __restrict__ bl, float* __restrict__ out, int n) {
    __shared__ float sW[600];
    __shared__ float sb[10];
    for (int i = threadIdx.x; i < 600; i += blockDim.x) sW[i] = Wl[i];
    if (threadIdx.x < 10) sb[threadIdx.x] = bl[threadIdx.x];
    __syncthreads();
    int t = blockIdx.x * blockDim.x + threadIdx.x;
    if (t >= n * 10) return;
    int i = t / 10, c = t % 10;
    float acc = sb[c];
    const float* r1 = o1 + i * HD;
    const float* r2 = o2 + i * HD;
    const float* r3 = o3 + i * HD;
    #pragma unroll
    for (int k = 0; k < HD; ++k) acc = fmaf(r1[k], sW[k * 10 + c], acc);
    #pragma unroll
    for (int k = 0; k < HD; ++k) acc = fmaf(r2[k], sW[(HD + k) * 10 + c], acc);
    #pragma unroll
    for (int k = 0; k < HD; ++k) acc = fmaf(r3[k], sW[(2 * HD + k) * 10 + c], acc);
    out[t] = acc;
}

extern "C" void kernel_launch(void* const* d_in, const int* in_sizes, int n_in,
                              void* d_out, int out_size, void* d_ws, size_t ws_size,
                              hipStream_t stream) {
    const float* x   = (const float*)d_in[0];
    const int*   ei  = (const int*)d_in[1];
    const float* ew  = (const float*)d_in[2];
    const float* W1  = (const float*)d_in[3];
    const float* b1  = (const float*)d_in[4];
    const float* g1  = (const float*)d_in[5];
    const float* be1 = (const float*)d_in[6];
    const float* W2  = (const float*)d_in[7];
    const float* b2  = (const float*)d_in[8];
    const float* g2  = (const float*)d_in[9];
    const float* be2 = (const float*)d_in[10];
    const float* W3  = (const float*)d_in[11];
    const float* b3  = (const float*)d_in[12];
    const float* Wl  = (const float*)d_in[13];
    const float* bl  = (const float*)d_in[14];
    float* out = (float*)d_out;

    const int F = in_sizes[3] / HD;       // 128
    const int N = in_sizes[0] / F;        // 100000
    const int E = in_sizes[2];            // 3200000
    const int* src = ei;
    const int* dst = ei + E;
    const int nbv = (N + 127) >> BSH;     // 782 buckets

    char* p = (char*)d_ws;
    auto alloc = [&](size_t bytes) -> void* {
        void* r = (void*)p;
        p += (bytes + 255) & ~(size_t)255;
        return r;
    };
    size_t nh4 = (size_t)N * HD * 4;                         // 8e6 B
    int2*  se      = (int2*) alloc((size_t)E * 8);           // CSR payload (src, ew)
    char*  regionA = (char*) alloc((size_t)E * 8);           // tmp -> hs|o3|o1r
    float* o2r     = (float*)alloc(nh4);
    float* dinv    = (float*)alloc((size_t)N * 4);
    int*   row_start = (int*)alloc((size_t)(N + 1) * 4);
    int*   bcnt    = (int*)  alloc(NBMAX * 4);
    int*   bstart  = (int*)  alloc((NBMAX + 1) * 4);
    int*   bcur    = (int*)  alloc(NBMAX * 4);
    float* stats   = (float*)alloc(80 * 4);   // sum1,sq1,sum2,sq2
    float* scsh    = (float*)alloc(80 * 4);   // sc1,sh1,sc2,sh2
    float* zero20  = (float*)alloc(20 * 4);
    float* W2p     = (float*)alloc(400 * 4);
    float* c2      = (float*)alloc(20 * 4);
    float* W3p     = (float*)alloc(400 * 4);
    float* c3      = (float*)alloc(20 * 4);
    float* Wlp     = (float*)alloc(600 * 4);
    float* blp     = (float*)alloc(12 * 4);

    int2*  tmp = (int2*)regionA;
    float* hs  = (float*)regionA;
    float* o3  = (float*)(regionA + nh4);
    float* o1r = (float*)(regionA + 2 * nh4);

    const int B = 256;
    const int GB = 512;                          // blocks for hist/scatter
    const int chunk = (E + GB - 1) / GB;         // 6250
    int gAgg = (2 * N + B - 1) / B;              // 782
    int gNC  = (N * 10 + B - 1) / B;

    // ---- graph build (shared by all 3 layers) ----
    hipLaunchKernelGGL(init_kernel, dim3(1), dim3(1024), 0, stream, bcnt, stats, zero20, nbv);
    hipLaunchKernelGGL(bucket_hist_kernel, dim3(GB), dim3(B), 0, stream, dst, bcnt, E, chunk, nbv);
    hipLaunchKernelGGL(bucket_scan_kernel, dim3(1), dim3(1024), 0, stream,
                       bcnt, bstart, bcur, row_start, N, E, nbv);
    hipLaunchKernelGGL(scatter_kernel, dim3(GB), dim3(B), 0, stream,
                       src, dst, ew, bcur, tmp, E, chunk, nbv);
    hipLaunchKernelGGL(finalize_kernel, dim3(nbv), dim3(B), 0, stream,
                       tmp, bstart, se, row_start, dinv, N);

    // ---- layer 1 (no upstream BN: cvec = 0, bias = b1) ----
    hipLaunchKernelGGL((gemm_kernel<128, 16>), dim3((N + 15) / 16), dim3(B), 0, stream,
                       x, W1, zero20, dinv, hs, N);
    hipLaunchKernelGGL((agg_kernel<true>), dim3(gAgg), dim3(B), 0, stream,
                       (const float4*)hs, dinv, row_start, se, b1, (float4*)o1r,
                       stats, stats + 20, N);
    hipLaunchKernelGGL(bn_finalize_kernel, dim3(1), dim3(64), 0, stream,
                       stats, stats + 20, g1, be1, scsh, scsh + 20, N);
    hipLaunchKernelGGL(adjust_w_kernel, dim3(1), dim3(512), 0, stream,
                       W2, scsh, scsh + 20, W2p, c2);

    // ---- layer 2 (BN1 scale in W2p, shift in c2 pre-agg; bias = raw b2) ----
    hipLaunchKernelGGL((gemm_kernel<HD, 64>), dim3((N + 63) / 64), dim3(B), 0, stream,
                       o1r, W2p, c2, dinv, hs, N);
    hipLaunchKernelGGL((agg_kernel<true>), dim3(gAgg), dim3(B), 0, stream,
                       (const float4*)hs, dinv, row_start, se, b2, (float4*)o2r,
                       stats + 40, stats + 60, N);
    hipLaunchKernelGGL(bn_finalize_kernel, dim3(1), dim3(64), 0, stream,
                       stats + 40, stats + 60, g2, be2, scsh + 40, scsh + 60, N);
    hipLaunchKernelGGL(adjust_w_kernel, dim3(1), dim3(512), 0, stream,
                       W3, scsh + 40, scsh + 60, W3p, c3);

    // ---- layer 3 (BN2 scale in W3p, shift in c3 pre-agg; bias = raw b3) ----
    hipLaunchKernelGGL((gemm_kernel<HD, 64>), dim3((N + 63) / 64), dim3(B), 0, stream,
                       o2r, W3p, c3, dinv, hs, N);
    hipLaunchKernelGGL((agg_kernel<false>), dim3(gAgg), dim3(B), 0, stream,
                       (const float4*)hs, dinv, row_start, se, b3, (float4*)o3,
                       nullptr, nullptr, N);

    // ---- final linear on raw o1r/o2r with BN folded into Wlp/blp (exact) ----
    hipLaunchKernelGGL(adjust_final_kernel, dim3(1), dim3(640), 0, stream,
                       Wl, bl, scsh, Wlp, blp);
    hipLaunchKernelGGL(final_kernel, dim3(gNC), dim3(B), 0, stream,
                       o1r, o2r, o3, Wlp, blp, out, N);
}

// Round 5
// 561.747 us; speedup vs baseline: 2.7268x; 1.2305x over previous
//
#include <hip/hip_runtime.h>
#include <hip/hip_bf16.h>
#include <hip/hip_fp16.h>

// NodeGCN: 3x GCNConv(H=20) + BN/ReLU + final linear, N=100K, E=3.2M.
// R4 changes vs R3:
//  - hs (the gathered per-node feature rows) stored as FP16: row 40B, total
//    4MB == per-XCD L2 size -> random gathers become L2-resident (was 8MB fp32
//    thrashing every XCD's 4MB L2: FETCH_SIZE 255MB == E*80B, pure L3 traffic).
//    All accumulation stays fp32; only the gather payload is fp16.
//  - agg: 4 threads per node (edge loop split 4 ways, shfl_xor(1,2) combine):
//    grid 782 -> 1563 blocks, occupancy 29% -> ~60%+ for latency hiding.
// R3 structure retained: bucketed counting-sort CSR build, BN scale folded into
// next W + shift carried pre-aggregation (cvec), BN folded into final linear.

#define HD 20
#define EPS 1e-5f
#define BSH 7            // 128 nodes per bucket
#define NBMAX 1024
#define CAP 8192         // max edges per bucket held in LDS (mean ~4092)

__global__ __launch_bounds__(1024)
void init_kernel(int* bcnt, float* stats, float* zero20, int nbv) {
    int t = threadIdx.x;
    if (t < nbv) bcnt[t] = 0;
    if (t < 80) stats[t] = 0.0f;
    if (t < HD) zero20[t] = 0.0f;
}

__global__ __launch_bounds__(256)
void bucket_hist_kernel(const int* __restrict__ dst, int* __restrict__ bcnt,
                        int E, int chunk, int nbv) {
    __shared__ int lh[NBMAX];
    for (int i = threadIdx.x; i < nbv; i += 256) lh[i] = 0;
    __syncthreads();
    int s = blockIdx.x * chunk;
    int e = s + chunk; if (e > E) e = E;
    for (int j = s + threadIdx.x; j < e; j += 256)
        atomicAdd(&lh[dst[j] >> BSH], 1);
    __syncthreads();
    for (int i = threadIdx.x; i < nbv; i += 256)
        if (lh[i]) atomicAdd(&bcnt[i], lh[i]);
}

// single block: exclusive scan bcnt[0..nbv) -> bstart, init bcur, row_start[N]=E
__global__ __launch_bounds__(1024)
void bucket_scan_kernel(const int* __restrict__ bcnt, int* __restrict__ bstart,
                        int* __restrict__ bcur, int* __restrict__ row_start,
                        int n, int E, int nbv) {
    __shared__ int s[1024];
    int t = threadIdx.x;
    int v = (t < nbv) ? bcnt[t] : 0;
    s[t] = v;
    __syncthreads();
    for (int off = 1; off < 1024; off <<= 1) {
        int u = (t >= off) ? s[t - off] : 0;
        __syncthreads();
        s[t] += u;
        __syncthreads();
    }
    if (t < nbv) { int st = s[t] - v; bstart[t] = st; bcur[t] = st; }
    if (t == 0) { bstart[nbv] = E; row_start[n] = E; }
}

// scatter edges into bucket-grouped tmp; payload packed (src | local<<20, ew)
__global__ __launch_bounds__(256)
void scatter_kernel(const int* __restrict__ src, const int* __restrict__ dst,
                    const float* __restrict__ ew, int* __restrict__ bcur,
                    int2* __restrict__ tmp, int E, int chunk, int nbv) {
    __shared__ int lh[NBMAX];
    __shared__ int lbase[NBMAX];
    for (int i = threadIdx.x; i < nbv; i += 256) lh[i] = 0;
    __syncthreads();
    int s = blockIdx.x * chunk;
    int e = s + chunk; if (e > E) e = E;
    for (int j = s + threadIdx.x; j < e; j += 256)
        atomicAdd(&lh[dst[j] >> BSH], 1);
    __syncthreads();
    for (int i = threadIdx.x; i < nbv; i += 256) {
        int c = lh[i];
        lbase[i] = c ? atomicAdd(&bcur[i], c) : 0;
        lh[i] = 0;                         // reuse as local cursor
    }
    __syncthreads();
    for (int j = s + threadIdx.x; j < e; j += 256) {
        int d = dst[j];
        int b = d >> BSH;
        int pos = atomicAdd(&lh[b], 1);
        tmp[lbase[b] + pos] = make_int2(src[j] | ((d & ((1 << BSH) - 1)) << 20),
                                        __float_as_int(ew[j]));
    }
}

// one block per bucket: in-LDS counting sort by local dst; emit CSR + row_start + dinv
__global__ __launch_bounds__(256)
void finalize_kernel(const int2* __restrict__ tmp, const int* __restrict__ bstart,
                     int2* __restrict__ se, int* __restrict__ row_start,
                     float* __restrict__ dinv, int n) {
    __shared__ int hist[128];
    __shared__ float degs[128];
    __shared__ int off[128];
    __shared__ int cur[128];
    __shared__ int2 stage[CAP];
    int b = blockIdx.x;
    int s0 = bstart[b], s1 = bstart[b + 1];
    int cnt = s1 - s0;
    int t = threadIdx.x;
    if (t < 128) { hist[t] = 0; degs[t] = 0.0f; cur[t] = 0; }
    __syncthreads();
    for (int j = s0 + t; j < s1; j += 256) {
        int2 r = tmp[j];
        int l = r.x >> 20;
        atomicAdd(&hist[l], 1);
        atomicAdd(&degs[l], __int_as_float(r.y));
    }
    __syncthreads();
    if (t < 128) off[t] = hist[t];
    __syncthreads();
    for (int o = 1; o < 128; o <<= 1) {           // inclusive scan
        int u = (t < 128 && t >= o) ? off[t - o] : 0;
        __syncthreads();
        if (t < 128) off[t] += u;
        __syncthreads();
    }
    if (t < 128) {
        int node = (b << BSH) + t;
        if (node < n) {
            row_start[node] = s0 + off[t] - hist[t];   // exclusive
            dinv[node] = rsqrtf(1.0f + degs[t]);
        }
    }
    __syncthreads();
    if (cnt <= CAP) {
        for (int j = s0 + t; j < s1; j += 256) {
            int2 r = tmp[j];
            int l = r.x >> 20;
            int p = (off[l] - hist[l]) + atomicAdd(&cur[l], 1);
            stage[p] = make_int2(r.x & 0xFFFFF, r.y);
        }
        __syncthreads();
        for (int k = t; k < cnt; k += 256) se[s0 + k] = stage[k];
    } else {   // overflow fallback (correctness net; not taken for this input)
        for (int j = s0 + t; j < s1; j += 256) {
            int2 r = tmp[j];
            int l = r.x >> 20;
            int p = (off[l] - hist[l]) + atomicAdd(&cur[l], 1);
            se[s0 + p] = make_int2(r.x & 0xFFFFF, r.y);
        }
    }
}

// hs[n,20](fp16) = ((in[n,FIN] @ W[FIN,20]) + cvec) * dinv[n]
// cvec carries the folded upstream-BN shift (sh @ W); zero for layer 1.
template<int FIN, int NPB>
__global__ __launch_bounds__(256)
void gemm_kernel(const float* __restrict__ in, const float* __restrict__ W,
                 const float* __restrict__ cvec, const float* __restrict__ dinv,
                 __half* __restrict__ hs, int n) {
    __shared__ float sWt[HD][FIN + 4];
    __shared__ float sIn[NPB][FIN + 4];
    __shared__ float sC[HD];
    for (int i = threadIdx.x; i < FIN * HD; i += 256) {
        int k = i / HD, f = i % HD;           // W row-major [k][f]
        sWt[f][k] = W[i];
    }
    if (threadIdx.x < HD) sC[threadIdx.x] = cvec[threadIdx.x];
    int base = blockIdx.x * NPB;
    int nb = n - base; if (nb > NPB) nb = NPB;
    int lim = n * FIN;
    const int Q = FIN / 4;
    for (int i = threadIdx.x; i < NPB * Q; i += 256) {
        int row = i / Q, c = (i % Q) * 4;
        int g = (base + row) * FIN + c;
        *(float4*)&sIn[row][c] = (g < lim) ? *(const float4*)&in[g]
                                           : make_float4(0.f, 0.f, 0.f, 0.f);
    }
    __syncthreads();
    for (int idx = threadIdx.x; idx < NPB * HD; idx += 256) {
        int nl = idx / HD, f = idx % HD;
        float4 a = make_float4(0.f, 0.f, 0.f, 0.f);
        #pragma unroll 4
        for (int k = 0; k < FIN; k += 4) {
            float4 x4 = *(const float4*)&sIn[nl][k];
            float4 w4 = *(const float4*)&sWt[f][k];
            a.x = fmaf(x4.x, w4.x, a.x);
            a.y = fmaf(x4.y, w4.y, a.y);
            a.z = fmaf(x4.z, w4.z, a.z);
            a.w = fmaf(x4.w, w4.w, a.w);
        }
        if (nl < nb)
            hs[(base + nl) * HD + f] = __float2half_rn(
                (((a.x + a.y) + (a.z + a.w)) + sC[f]) * dinv[base + nl]);
    }
}

#define FMA4(A, V, W) \
    A.x = fmaf(V.x, W, A.x); A.y = fmaf(V.y, W, A.y); \
    A.z = fmaf(V.z, W, A.z); A.w = fmaf(V.w, W, A.w);

__device__ __forceinline__ float4 unpack_h4(uint2 u) {
    float2 f0 = __half22float2(*reinterpret_cast<const __half2*>(&u.x));
    float2 f1 = __half22float2(*reinterpret_cast<const __half2*>(&u.y));
    return make_float4(f0.x, f0.y, f1.x, f1.y);
}

// one node per thread-QUAD; lanes take every 4th edge; shfl_xor(1,2) combine.
// hs rows are fp16 (uint2 = 4 halfs), accumulation fp32.
template<bool DO_STATS>
__global__ __launch_bounds__(256)
void agg_kernel(const uint2* __restrict__ hsh, const float* __restrict__ dinv,
                const int* __restrict__ row_start, const int2* __restrict__ se,
                const float* __restrict__ bias, float4* __restrict__ out,
                float* __restrict__ stat_sum, float* __restrict__ stat_sq, int n) {
    __shared__ float ls[HD], lq[HD];
    if (DO_STATS) {
        if (threadIdx.x < HD) { ls[threadIdx.x] = 0.0f; lq[threadIdx.x] = 0.0f; }
        __syncthreads();
    }
    int t = blockIdx.x * blockDim.x + threadIdx.x;
    int i = t >> 2, lane4 = t & 3;
    if (i < n) {
        float di = dinv[i];
        int s0 = row_start[i], s1 = row_start[i + 1];
        float4 a0, a1, a2, a3, a4;
        if (lane4 == 0) {
            const uint2* s = hsh + i * 5;
            a0 = unpack_h4(s[0]); a1 = unpack_h4(s[1]); a2 = unpack_h4(s[2]);
            a3 = unpack_h4(s[3]); a4 = unpack_h4(s[4]);
        } else {
            a0 = a1 = a2 = a3 = a4 = make_float4(0.f, 0.f, 0.f, 0.f);
        }
        for (int j = s0 + lane4; j < s1; j += 4) {
            int2 e = se[j];
            float w = __int_as_float(e.y);
            const uint2* r = hsh + e.x * 5;
            uint2 u0 = r[0], u1 = r[1], u2 = r[2], u3 = r[3], u4 = r[4];
            float4 v0 = unpack_h4(u0), v1 = unpack_h4(u1), v2 = unpack_h4(u2);
            float4 v3 = unpack_h4(u3), v4 = unpack_h4(u4);
            FMA4(a0, v0, w) FMA4(a1, v1, w) FMA4(a2, v2, w)
            FMA4(a3, v3, w) FMA4(a4, v4, w)
        }
        #define RED4(A) \
            A.x += __shfl_xor(A.x, 1); A.y += __shfl_xor(A.y, 1); \
            A.z += __shfl_xor(A.z, 1); A.w += __shfl_xor(A.w, 1); \
            A.x += __shfl_xor(A.x, 2); A.y += __shfl_xor(A.y, 2); \
            A.z += __shfl_xor(A.z, 2); A.w += __shfl_xor(A.w, 2);
        RED4(a0) RED4(a1) RED4(a2) RED4(a3) RED4(a4)
        if (lane4 == 0) {
            float4 acc[5] = {a0, a1, a2, a3, a4};
            #pragma unroll
            for (int q = 0; q < 5; ++q) {
                float4 bb = *(const float4*)(bias + 4 * q);
                float4 v;
                v.x = fmaxf(fmaf(acc[q].x, di, bb.x), 0.0f);
                v.y = fmaxf(fmaf(acc[q].y, di, bb.y), 0.0f);
                v.z = fmaxf(fmaf(acc[q].z, di, bb.z), 0.0f);
                v.w = fmaxf(fmaf(acc[q].w, di, bb.w), 0.0f);
                out[i * 5 + q] = v;
                if (DO_STATS) {
                    int f = 4 * q;
                    atomicAdd(&ls[f + 0], v.x); atomicAdd(&lq[f + 0], v.x * v.x);
                    atomicAdd(&ls[f + 1], v.y); atomicAdd(&lq[f + 1], v.y * v.y);
                    atomicAdd(&ls[f + 2], v.z); atomicAdd(&lq[f + 2], v.z * v.z);
                    atomicAdd(&ls[f + 3], v.w); atomicAdd(&lq[f + 3], v.w * v.w);
                }
            }
        }
    }
    if (DO_STATS) {
        __syncthreads();
        if (threadIdx.x < HD) {
            atomicAdd(&stat_sum[threadIdx.x], ls[threadIdx.x]);
            atomicAdd(&stat_sq[threadIdx.x], lq[threadIdx.x]);
        }
    }
}

__global__ __launch_bounds__(64)
void bn_finalize_kernel(const float* __restrict__ sum, const float* __restrict__ sq,
                        const float* __restrict__ g, const float* __restrict__ be,
                        float* __restrict__ scale, float* __restrict__ shift, int n) {
    int t = threadIdx.x;
    if (t < HD) {
        float inv_n = 1.0f / (float)n;
        float m = sum[t] * inv_n;
        float var = sq[t] * inv_n - m * m;
        float sc = g[t] * rsqrtf(var + EPS);
        scale[t] = sc;
        shift[t] = be[t] - m * sc;
    }
}

// Wp[k][f] = sc[k]*W[k][f];  cvec[f] = sum_k sh[k]*W[k][f]   (20x20)
__global__ __launch_bounds__(512)
void adjust_w_kernel(const float* __restrict__ W, const float* __restrict__ sc,
                     const float* __restrict__ sh, float* __restrict__ Wp,
                     float* __restrict__ cvec) {
    int t = threadIdx.x;
    if (t < HD * HD) Wp[t] = sc[t / HD] * W[t];
    if (t < HD) {
        float acc = 0.0f;
        #pragma unroll
        for (int k = 0; k < HD; ++k) acc = fmaf(sh[k], W[k * HD + t], acc);
        cvec[t] = acc;
    }
}

// Wlp rows 0..19 *= sc1, 20..39 *= sc2; blp = bl + sh1@Wl[0:20] + sh2@Wl[20:40]
__global__ __launch_bounds__(640)
void adjust_final_kernel(const float* __restrict__ Wl, const float* __restrict__ bl,
                         const float* __restrict__ scsh,
                         float* __restrict__ Wlp, float* __restrict__ blp) {
    int t = threadIdx.x;
    if (t < 600) {
        int k = t / 10;
        float s = (k < 20) ? scsh[k] : (k < 40) ? scsh[40 + (k - 20)] : 1.0f;
        Wlp[t] = s * Wl[t];
    }
    if (t < 10) {
        float acc = bl[t];
        #pragma unroll
        for (int k = 0; k < HD; ++k) acc = fmaf(scsh[20 + k], Wl[k * 10 + t], acc);
        #pragma unroll
        for (int k = 0; k < HD; ++k) acc = fmaf(scsh[60 + k], Wl[(HD + k) * 10 + t], acc);
        blp[t] = acc;
    }
}

__global__ __launch_bounds__(256)
void final_kernel(const float* __restrict__ o1, const float* __restrict__ o2,
                  const float* __restrict__ o3, const float* __restrict__ Wl,
                  const float* __restrict__ bl, float* __restrict__ out, int n) {
    __shared__ float sW[600];
    __shared__ float sb[10];
    for (int i = threadIdx.x; i < 600; i += blockDim.x) sW[i] = Wl[i];
    if (threadIdx.x < 10) sb[threadIdx.x] = bl[threadIdx.x];
    __syncthreads();
    int t = blockIdx.x * blockDim.x + threadIdx.x;
    if (t >= n * 10) return;
    int i = t / 10, c = t % 10;
    float acc = sb[c];
    const float* r1 = o1 + i * HD;
    const float* r2 = o2 + i * HD;
    const float* r3 = o3 + i * HD;
    #pragma unroll
    for (int k = 0; k < HD; ++k) acc = fmaf(r1[k], sW[k * 10 + c], acc);
    #pragma unroll
    for (int k = 0; k < HD; ++k) acc = fmaf(r2[k], sW[(HD + k) * 10 + c], acc);
    #pragma unroll
    for (int k = 0; k < HD; ++k) acc = fmaf(r3[k], sW[(2 * HD + k) * 10 + c], acc);
    out[t] = acc;
}

extern "C" void kernel_launch(void* const* d_in, const int* in_sizes, int n_in,
                              void* d_out, int out_size, void* d_ws, size_t ws_size,
                              hipStream_t stream) {
    const float* x   = (const float*)d_in[0];
    const int*   ei  = (const int*)d_in[1];
    const float* ew  = (const float*)d_in[2];
    const float* W1  = (const float*)d_in[3];
    const float* b1  = (const float*)d_in[4];
    const float* g1  = (const float*)d_in[5];
    const float* be1 = (const float*)d_in[6];
    const float* W2  = (const float*)d_in[7];
    const float* b2  = (const float*)d_in[8];
    const float* g2  = (const float*)d_in[9];
    const float* be2 = (const float*)d_in[10];
    const float* W3  = (const float*)d_in[11];
    const float* b3  = (const float*)d_in[12];
    const float* Wl  = (const float*)d_in[13];
    const float* bl  = (const float*)d_in[14];
    float* out = (float*)d_out;

    const int F = in_sizes[3] / HD;       // 128
    const int N = in_sizes[0] / F;        // 100000
    const int E = in_sizes[2];            // 3200000
    const int* src = ei;
    const int* dst = ei + E;
    const int nbv = (N + 127) >> BSH;     // 782 buckets

    char* p = (char*)d_ws;
    auto alloc = [&](size_t bytes) -> void* {
        void* r = (void*)p;
        p += (bytes + 255) & ~(size_t)255;
        return r;
    };
    size_t nh4 = (size_t)N * HD * 4;                         // 8e6 B
    int2*  se      = (int2*) alloc((size_t)E * 8);           // CSR payload (src, ew)
    char*  regionA = (char*) alloc((size_t)E * 8);           // tmp -> hs|o3|o1r
    float* o2r     = (float*)alloc(nh4);
    float* dinv    = (float*)alloc((size_t)N * 4);
    int*   row_start = (int*)alloc((size_t)(N + 1) * 4);
    int*   bcnt    = (int*)  alloc(NBMAX * 4);
    int*   bstart  = (int*)  alloc((NBMAX + 1) * 4);
    int*   bcur    = (int*)  alloc(NBMAX * 4);
    float* stats   = (float*)alloc(80 * 4);   // sum1,sq1,sum2,sq2
    float* scsh    = (float*)alloc(80 * 4);   // sc1,sh1,sc2,sh2
    float* zero20  = (float*)alloc(20 * 4);
    float* W2p     = (float*)alloc(400 * 4);
    float* c2      = (float*)alloc(20 * 4);
    float* W3p     = (float*)alloc(400 * 4);
    float* c3      = (float*)alloc(20 * 4);
    float* Wlp     = (float*)alloc(600 * 4);
    float* blp     = (float*)alloc(12 * 4);

    int2*   tmp = (int2*)regionA;
    __half* hs  = (__half*)regionA;                 // 4 MB fp16, fits per-XCD L2
    float*  o3  = (float*)(regionA + nh4);
    float*  o1r = (float*)(regionA + 2 * nh4);

    const int B = 256;
    const int GB = 512;                          // blocks for hist/scatter
    const int chunk = (E + GB - 1) / GB;         // 6250
    int gAgg = (4 * N + B - 1) / B;              // 1563 (4 threads/node)
    int gNC  = (N * 10 + B - 1) / B;

    // ---- graph build (shared by all 3 layers) ----
    hipLaunchKernelGGL(init_kernel, dim3(1), dim3(1024), 0, stream, bcnt, stats, zero20, nbv);
    hipLaunchKernelGGL(bucket_hist_kernel, dim3(GB), dim3(B), 0, stream, dst, bcnt, E, chunk, nbv);
    hipLaunchKernelGGL(bucket_scan_kernel, dim3(1), dim3(1024), 0, stream,
                       bcnt, bstart, bcur, row_start, N, E, nbv);
    hipLaunchKernelGGL(scatter_kernel, dim3(GB), dim3(B), 0, stream,
                       src, dst, ew, bcur, tmp, E, chunk, nbv);
    hipLaunchKernelGGL(finalize_kernel, dim3(nbv), dim3(B), 0, stream,
                       tmp, bstart, se, row_start, dinv, N);

    // ---- layer 1 (no upstream BN: cvec = 0, bias = b1) ----
    hipLaunchKernelGGL((gemm_kernel<128, 16>), dim3((N + 15) / 16), dim3(B), 0, stream,
                       x, W1, zero20, dinv, hs, N);
    hipLaunchKernelGGL((agg_kernel<true>), dim3(gAgg), dim3(B), 0, stream,
                       (const uint2*)hs, dinv, row_start, se, b1, (float4*)o1r,
                       stats, stats + 20, N);
    hipLaunchKernelGGL(bn_finalize_kernel, dim3(1), dim3(64), 0, stream,
                       stats, stats + 20, g1, be1, scsh, scsh + 20, N);
    hipLaunchKernelGGL(adjust_w_kernel, dim3(1), dim3(512), 0, stream,
                       W2, scsh, scsh + 20, W2p, c2);

    // ---- layer 2 (BN1 scale in W2p, shift in c2 pre-agg; bias = raw b2) ----
    hipLaunchKernelGGL((gemm_kernel<HD, 64>), dim3((N + 63) / 64), dim3(B), 0, stream,
                       o1r, W2p, c2, dinv, hs, N);
    hipLaunchKernelGGL((agg_kernel<true>), dim3(gAgg), dim3(B), 0, stream,
                       (const uint2*)hs, dinv, row_start, se, b2, (float4*)o2r,
                       stats + 40, stats + 60, N);
    hipLaunchKernelGGL(bn_finalize_kernel, dim3(1), dim3(64), 0, stream,
                       stats + 40, stats + 60, g2, be2, scsh + 40, scsh + 60, N);
    hipLaunchKernelGGL(adjust_w_kernel, dim3(1), dim3(512), 0, stream,
                       W3, scsh + 40, scsh + 60, W3p, c3);

    // ---- layer 3 (BN2 scale in W3p, shift in c3 pre-agg; bias = raw b3) ----
    hipLaunchKernelGGL((gemm_kernel<HD, 64>), dim3((N + 63) / 64), dim3(B), 0, stream,
                       o2r, W3p, c3, dinv, hs, N);
    hipLaunchKernelGGL((agg_kernel<false>), dim3(gAgg), dim3(B), 0, stream,
                       (const uint2*)hs, dinv, row_start, se, b3, (float4*)o3,
                       nullptr, nullptr, N);

    // ---- final linear on raw o1r/o2r with BN folded into Wlp/blp (exact) ----
    hipLaunchKernelGGL(adjust_final_kernel, dim3(1), dim3(640), 0, stream,
                       Wl, bl, scsh, Wlp, blp);
    hipLaunchKernelGGL(final_kernel, dim3(gNC), dim3(B), 0, stream,
                       o1r, o2r, o3, Wlp, blp, out, N);
}